// Round 4
// baseline (211.246 us; speedup 1.0000x reference)
//
#include <hip/hip_runtime.h>
#include <math.h>

// x, x_r: (1, 3, 32, 512, 512) fp32. size=64 -> hc=wc=32, nh=nw=16.
// P[t,ph,pw] = mean over (c=3, 32x32) of |x - x_r|/2   (3072 elems/patch)
// out = log( mean_t( max(0, max_{ph,pw} P) ) )  -- scalar fp32.
//
// Kernel 1: 3072 blocks x 256 thr. Block b covers a CONTIGUOUS 2048-float4
//   chunk (16 rows x 512 cols of one (ch,t) frame = half of a (ch,t,ph)
//   stripe split by rows). f4 idx = i*256+tid -> col4 = tid&127 -> pw bin
//   = (tid&127)>>3 is CONSTANT per thread -> scalar accumulator.
//   All 16 loads (8 per input) are issued BEFORE a sched_barrier(0), forcing
//   the compiler to keep all results live (VGPR ~80) -> 16 loads in flight
//   per thread -> max MLP. Per-chunk 16-bin partials -> ws (no atomics).
// Kernel 2: one 1024-thread block: sum 6 chunk-contributions per patch
//   (3 ch x 2 row-halves), per-t max, clamp, mean, log.

__global__ __launch_bounds__(256) void patch_sum_kernel(
    const float* __restrict__ x, const float* __restrict__ xr,
    float* __restrict__ part) {
  const int b   = blockIdx.x;        // 0..3071, chunk = contiguous 2048 f4
  const int tid = threadIdx.x;
  const float4* __restrict__ a4 = (const float4*)x  + (size_t)b * 2048;
  const float4* __restrict__ c4 = (const float4*)xr + (size_t)b * 2048;

  float4 a[8], c[8];
#pragma unroll
  for (int i = 0; i < 8; ++i) a[i] = a4[i * 256 + tid];
#pragma unroll
  for (int i = 0; i < 8; ++i) c[i] = c4[i * 256 + tid];
  __builtin_amdgcn_sched_barrier(0);   // nothing moves across: all 16 loads
                                       // issued, results pinned live

  float s0 = 0.f, s1 = 0.f, s2 = 0.f, s3 = 0.f;
#pragma unroll
  for (int i = 0; i < 8; ++i) {
    s0 += fabsf(a[i].x - c[i].x);
    s1 += fabsf(a[i].y - c[i].y);
    s2 += fabsf(a[i].z - c[i].z);
    s3 += fabsf(a[i].w - c[i].w);
  }
  float acc = (s0 + s1) + (s2 + s3);

  // 16 pw bins; thread bin = (tid&127)>>3. Reduce 8 consecutive lanes, then
  // 32 leaders (m = tid>>3) land in LDS; bin = m&15; combine pairs.
  acc += __shfl_down(acc, 4, 8);
  acc += __shfl_down(acc, 2, 8);
  acc += __shfl_down(acc, 1, 8);
  __shared__ float s[32];
  if ((tid & 7) == 0) s[tid >> 3] = acc;
  __syncthreads();
  // part[b*16 + pw]; b = ch*1024 + t*32 + ph*2 + half
  if (tid < 16) part[(size_t)b * 16 + tid] = s[tid] + s[tid + 16];
}

__global__ __launch_bounds__(1024) void finalize_kernel(
    const float* __restrict__ part, float* __restrict__ out) {
  const int tid = threadIdx.x;
  const int t = tid >> 5;             // 0..31
  const int j = tid & 31;
  float m = -1e30f;
#pragma unroll
  for (int k = 0; k < 8; ++k) {
    int p = t * 256 + j + 32 * k;     // patch id within frame t
    int ph = (p >> 4) & 15;
    int pw = p & 15;
    float v = 0.f;
#pragma unroll
    for (int ch = 0; ch < 3; ++ch) {
#pragma unroll
      for (int half = 0; half < 2; ++half) {
        int idx = ((ch << 10) + (t << 5) + (ph << 1) + half) * 16 + pw;
        v += part[idx];
      }
    }
    m = fmaxf(m, v);
  }
#pragma unroll
  for (int o = 16; o > 0; o >>= 1) m = fmaxf(m, __shfl_down(m, o, 32));
  __shared__ float s[32];
  if (j == 0) s[t] = fmaxf(m * (0.5f / 3072.0f), 0.f);  // scale + clamp at 0
  __syncthreads();
  if (tid < 32) {
    float v = s[tid];
#pragma unroll
    for (int o = 16; o > 0; o >>= 1) v += __shfl_down(v, o, 32);
    if (tid == 0) out[0] = logf(v * (1.0f / 32.0f));
  }
}

extern "C" void kernel_launch(void* const* d_in, const int* in_sizes, int n_in,
                              void* d_out, int out_size, void* d_ws, size_t ws_size,
                              hipStream_t stream) {
  const float* x  = (const float*)d_in[0];
  const float* xr = (const float*)d_in[1];
  float* part = (float*)d_ws;        // 3072*16 floats = 192 KB scratch
  float* out  = (float*)d_out;

  patch_sum_kernel<<<3072, 256, 0, stream>>>(x, xr, part);
  finalize_kernel<<<1, 1024, 0, stream>>>(part, out);
}